// Round 2
// baseline (108.616 us; speedup 1.0000x reference)
//
#include <hip/hip_runtime.h>
#include <stdint.h>

// Problem constants (from reference setup_inputs)
#define BATCH 4096
#define ISZ   512
#define OSZ   512
#define KDIM  4096           // contraction dim: k = i*8 + d

// GEMM tiling (R8: 256x256 tile, BK=32, ring-4 LDS, 8-phase-style schedule)
#define BM 256
#define BN 256
#define BK 32
#define SPLITK 8
#define KPER (KDIM / SPLITK)     // 512
#define NT   (KPER / BK)         // 16 K-tiles per block

typedef __bf16 bf16x8 __attribute__((ext_vector_type(8)));
typedef float  f32x4  __attribute__((ext_vector_type(4)));

__device__ __forceinline__ unsigned short f2bf(float f) {
    uint32_t u = __float_as_uint(f);
    u = (u + 0x7FFFu + ((u >> 16) & 1u)) >> 16;
    return (unsigned short)u;
}

// prep: blocks [0,2048) coef fp32 [O][I][D] -> bf16 [O][K] (k-contiguous);
// blocks [2048,4096): jacobi8(tanh(x)) -> A bf16 [BATCH][KDIM], 4 x/thread
// (R8: float4 x loads). Jacobi computed ONCE (R7 win: was duplicated in gemm).
#define NB_CONV 2048         // (OSZ*KDIM/4) / 256
#define NB_JAC  2048         // (BATCH*ISZ/4) / 256
__global__ __launch_bounds__(256) void prep(
    const float* __restrict__ coef, unsigned short* __restrict__ coefb,
    const float* __restrict__ X,    unsigned short* __restrict__ Ab)
{
    const int b = blockIdx.x;
    if (b < NB_CONV) {
        int idx = b * 256 + threadIdx.x;
        float4 v = reinterpret_cast<const float4*>(coef)[idx];
        uint2 o;
        o.x = (uint32_t)f2bf(v.x) | ((uint32_t)f2bf(v.y) << 16);
        o.y = (uint32_t)f2bf(v.z) | ((uint32_t)f2bf(v.w) << 16);
        reinterpret_cast<uint2*>(coefb)[idx] = o;
    } else {
        int idx = (b - NB_CONV) * 256 + threadIdx.x;   // over [BATCH*ISZ/4]
        float4 xv = reinterpret_cast<const float4*>(X)[idx];
        const float xs[4] = {xv.x, xv.y, xv.z, xv.w};
        #pragma unroll
        for (int j = 0; j < 4; ++j) {
            // tanh(x) = 1 - 2/(exp(2x)+1); err ~1e-6 << bf16 ulp
            float e  = __expf(2.0f * xs[j]);
            float t  = 1.0f - 2.0f * __builtin_amdgcn_rcpf(e + 1.0f);
            float p0 = 1.0f;
            float p1 = 2.0f * t;
            float p2 = (1.875f     * t) * p1 - 0.75f       * p0;
            float p3 = (1.8666667f * t) * p2 - 0.8f        * p1;
            float p4 = (1.875f     * t) * p3 - 0.83333333f * p2;
            float p5 = (1.8857143f * t) * p4 - 0.85714287f * p3;
            float p6 = (1.8958333f * t) * p5 - 0.875f      * p4;
            float p7 = (1.9047619f * t) * p6 - 0.88888889f * p5;
            uint4 o;
            o.x = (uint32_t)f2bf(p0) | ((uint32_t)f2bf(p1) << 16);
            o.y = (uint32_t)f2bf(p2) | ((uint32_t)f2bf(p3) << 16);
            o.z = (uint32_t)f2bf(p4) | ((uint32_t)f2bf(p5) << 16);
            o.w = (uint32_t)f2bf(p6) | ((uint32_t)f2bf(p7) << 16);
            reinterpret_cast<uint4*>(Ab)[idx * 4 + j] = o;
        }
    }
}

#define SB __builtin_amdgcn_sched_barrier(0)
#define VM8 asm volatile("s_waitcnt vmcnt(8)" ::: "memory")
#define VM0 asm volatile("s_waitcnt vmcnt(0)" ::: "memory")

// R8 gemm: T3+T4+T5 port (8-phase-style). 256x256x(K=512/z) per block,
// 8 waves (2Mx4N), per-wave 128x64 = 8x4 frags of mfma_f32_16x16x32_bf16.
// Ring-4 LDS (A+B 32KB per K-tile of BK=32; 128KB total, 1 block/CU).
// Prefetch distance 3: while computing tile t, stage tile t+3 (4 loads/thr,
// 2 in each phase). End-of-tile s_waitcnt vmcnt(8) drains exactly L(t+1)
// (issued 2 tiles ago), leaving L(t+2),L(t+3) = 8 loads in flight -> no
// vmcnt(0) drain in the main loop (T4). Raw s_barrier + sched_barrier(0)
// pins (NOT __syncthreads, which forces vmcnt(0)). setprio(1) around each
// 16-MFMA cluster (T5; pays only with phase role-split).
// Wait-count induction: prologue stages L0,L1,L2 (12 loads), VM8 drains L0.
// End of tile t (t<13): outstanding L(t+1),L(t+2),L(t+3)=12; VM8 drains
// L(t+1) needed by t+1. Tail t=13,14: no staging -> VM0 (loads long since
// issued; drain is cheap). WAR: L(t+3) overwrites buf[(t-1)&3], last read
// in tile t-1 whose final barrier precedes the issue.
// LDS layout (both-sides-or-neither, rule #21): paired-row XOR swizzle
// slot = (r>>1)*8 + (((r&1)*4 + c) ^ ((r>>1)&7)); same map inverted on the
// per-lane global SOURCE addr, LDS dest linear (gload_lds contract:
// wave-uniform base + lane*16). Bank profile == proven zero-conflict R2-R7
// map (2 lanes/bank for b128 reads = free, m136).
__global__ __launch_bounds__(512, 2) void gemm_8p(
    const unsigned short* __restrict__ Am,  // [BATCH][KDIM] bf16 bits
    const unsigned short* __restrict__ Bm,  // [OSZ][KDIM] bf16 bits
    unsigned short* __restrict__ Cp,        // [SPLITK][M][N] bf16 partials
    int M, int N, int K)
{
    __shared__ __align__(16) unsigned short As[4][BM * BK];   // 4 x 16 KB
    __shared__ __align__(16) unsigned short Bs[4][BN * BK];   // 4 x 16 KB

    const int tid  = threadIdx.x;
    const int wave = tid >> 6;
    const int lane = tid & 63;
    const int wm   = (wave >> 2) * 128;     // wave row offset (2 M-groups)
    const int wn   = (wave & 3) * 64;       // wave col offset (4 N-groups)
    const int mrow = lane & 15;
    const int kc   = lane >> 4;             // 16B chunk col within BK=32

    // XCD-aware bijective decode: 256 wgs, 8 XCDs, 32/chunk. XCD x owns
    // z-slice x: A panel 4MB + B 0.5MB ~ its private L2.
    const int wg  = blockIdx.x;
    const int swz = (wg & 7) * 32 + (wg >> 3);
    const int z   = swz >> 5;
    const int rr  = swz & 31;
    const int by  = rr >> 4;                // 0..1
    const int bx  = rr & 15;                // 0..15

    const size_t baseA = (size_t)bx * BM * K;
    const size_t baseB = (size_t)by * BN * K;
    const int kbeg = z * KPER;

    f32x4 acc[8][4] = {};

    // Loop-invariant frag LDS offsets (ushort units)
    int aoff[8], boff[4];
    #pragma unroll
    for (int mi = 0; mi < 8; ++mi) {
        int r = wm + mi * 16 + mrow, g = r >> 1;
        aoff[mi] = (g * 8 + ((((r & 1) << 2) + kc) ^ (g & 7))) * 8;
    }
    #pragma unroll
    for (int ni = 0; ni < 4; ++ni) {
        int r = wn + ni * 16 + mrow, g = r >> 1;
        boff[ni] = (g * 8 + ((((r & 1) << 2) + kc) ^ (g & 7))) * 8;
    }
    // Loop-invariant staging source offsets (inverse of the slot map):
    // chunk s -> g=s>>3, cc=(s&7)^(g&7), row=2g+(cc>>2), col8=cc&3
    int sOff[2];
    #pragma unroll
    for (int it = 0; it < 2; ++it) {
        int s = it * 512 + tid;
        int g = s >> 3, cc = (s & 7) ^ (g & 7);
        sOff[it] = (2 * g + (cc >> 2)) * K + (cc & 3) * 8;
    }

    auto stageA = [&](int tt) {
        unsigned short* dst = &As[tt & 3][0];
        const unsigned short* src = Am + baseA + kbeg + tt * BK;
        #pragma unroll
        for (int it = 0; it < 2; ++it)
            __builtin_amdgcn_global_load_lds(
                (const __attribute__((address_space(1))) uint32_t*)(src + sOff[it]),
                (__attribute__((address_space(3))) uint32_t*)
                    (dst + (size_t)(it * 512 + wave * 64) * 8), 16, 0, 0);
    };
    auto stageB = [&](int tt) {
        unsigned short* dst = &Bs[tt & 3][0];
        const unsigned short* src = Bm + baseB + kbeg + tt * BK;
        #pragma unroll
        for (int it = 0; it < 2; ++it)
            __builtin_amdgcn_global_load_lds(
                (const __attribute__((address_space(1))) uint32_t*)(src + sOff[it]),
                (__attribute__((address_space(3))) uint32_t*)
                    (dst + (size_t)(it * 512 + wave * 64) * 8), 16, 0, 0);
    };

#define KTILE(T, STG, WAITSTMT)                                            \
  {                                                                        \
    const unsigned short* Ap = &As[(T) & 3][0];                            \
    const unsigned short* Bp = &Bs[(T) & 3][0];                            \
    bf16x8 aF[4], bF[4];                                                   \
    SB;                                                                    \
    _Pragma("unroll")                                                      \
    for (int mi = 0; mi < 4; ++mi)                                         \
      aF[mi] = *reinterpret_cast<const bf16x8*>(Ap + aoff[mi]);            \
    _Pragma("unroll")                                                      \
    for (int ni = 0; ni < 4; ++ni)                                         \
      bF[ni] = *reinterpret_cast<const bf16x8*>(Bp + boff[ni]);            \
    if (STG) stageA((T) + 3);                                              \
    SB; __builtin_amdgcn_s_barrier(); SB;                                  \
    __builtin_amdgcn_s_setprio(1);                                         \
    _Pragma("unroll")                                                      \
    for (int mi = 0; mi < 4; ++mi)                                         \
      _Pragma("unroll")                                                    \
      for (int ni = 0; ni < 4; ++ni)                                       \
        acc[mi][ni] = __builtin_amdgcn_mfma_f32_16x16x32_bf16(             \
            aF[mi], bF[ni], acc[mi][ni], 0, 0, 0);                         \
    __builtin_amdgcn_s_setprio(0);                                         \
    SB; __builtin_amdgcn_s_barrier();                                      \
    SB;                                                                    \
    _Pragma("unroll")                                                      \
    for (int mi = 0; mi < 4; ++mi)                                         \
      aF[mi] = *reinterpret_cast<const bf16x8*>(Ap + aoff[4 + mi]);        \
    if (STG) stageB((T) + 3);                                              \
    SB; __builtin_amdgcn_s_barrier(); SB;                                  \
    __builtin_amdgcn_s_setprio(1);                                         \
    _Pragma("unroll")                                                      \
    for (int mi = 0; mi < 4; ++mi)                                         \
      _Pragma("unroll")                                                    \
      for (int ni = 0; ni < 4; ++ni)                                       \
        acc[4 + mi][ni] = __builtin_amdgcn_mfma_f32_16x16x32_bf16(         \
            aF[mi], bF[ni], acc[4 + mi][ni], 0, 0, 0);                     \
    __builtin_amdgcn_s_setprio(0);                                         \
    SB; WAITSTMT; __builtin_amdgcn_s_barrier();                            \
  }

    // Prologue: stage tiles 0,1,2 (12 loads); drain L0, keep L1,L2 flying.
    stageA(0); stageB(0);
    stageA(1); stageB(1);
    stageA(2); stageB(2);
    VM8;
    __builtin_amdgcn_s_barrier();

    for (int t = 0; t < NT - 3; ++t)        // t = 0..12, stages t+3 <= 15
        KTILE(t, true, VM8);
    KTILE(NT - 3, false, VM0);              // t = 13: drain L(14),L(15)
    KTILE(NT - 2, false, VM0);              // t = 14
    KTILE(NT - 1, false, VM0);              // t = 15

    // bf16 partials, plain stores. C/D layout (m89-verified):
    // col = lane&15, row = (lane>>4)*4 + r
    unsigned short* Cz = Cp + (size_t)z * M * N;
    const int orow = bx * BM + wm + (lane >> 4) * 4;
    const int ocol = by * BN + wn + (lane & 15);
    #pragma unroll
    for (int mi = 0; mi < 8; ++mi)
        #pragma unroll
        for (int ni = 0; ni < 4; ++ni)
            #pragma unroll
            for (int r = 0; r < 4; ++r)
                Cz[(size_t)(orow + mi * 16 + r) * N + ocol + ni * 16] =
                    f2bf(acc[mi][ni][r]);
}

// out = sum over SPLITK bf16 partials (fp32 accumulate), 8 outputs/thread
__global__ __launch_bounds__(256) void reduce_k(
    const unsigned short* __restrict__ part, float* __restrict__ out, int n8)
{
    int idx = blockIdx.x * 256 + threadIdx.x;
    if (idx >= n8) return;
    const uint4* p = reinterpret_cast<const uint4*>(part);   // 8 bf16 / uint4
    float s[8] = {};
    #pragma unroll
    for (int z = 0; z < SPLITK; ++z) {
        uint4 v = p[(size_t)z * n8 + idx];
        s[0] += __uint_as_float((v.x & 0xFFFFu) << 16);
        s[1] += __uint_as_float(v.x & 0xFFFF0000u);
        s[2] += __uint_as_float((v.y & 0xFFFFu) << 16);
        s[3] += __uint_as_float(v.y & 0xFFFF0000u);
        s[4] += __uint_as_float((v.z & 0xFFFFu) << 16);
        s[5] += __uint_as_float(v.z & 0xFFFF0000u);
        s[6] += __uint_as_float((v.w & 0xFFFFu) << 16);
        s[7] += __uint_as_float(v.w & 0xFFFF0000u);
    }
    float4 o0 = {s[0], s[1], s[2], s[3]};
    float4 o1 = {s[4], s[5], s[6], s[7]};
    reinterpret_cast<float4*>(out)[2 * idx]     = o0;
    reinterpret_cast<float4*>(out)[2 * idx + 1] = o1;
}

extern "C" void kernel_launch(void* const* d_in, const int* in_sizes, int n_in,
                              void* d_out, int out_size, void* d_ws, size_t ws_size,
                              hipStream_t stream)
{
    const float* x    = (const float*)d_in[0];   // [4096][512]
    const float* coef = (const float*)d_in[1];   // [512][512][8]
    float* out = (float*)d_out;                  // [4096][512]

    // workspace: bf16 partials [SPLITK][4096][512] (33.5 MB)
    //          + coef bf16 [512][4096]             (4.2 MB)
    //          + A bf16 [4096][4096]               (33.5 MB)
    unsigned short* part  = (unsigned short*)d_ws;
    unsigned short* coefb = part  + (size_t)SPLITK * BATCH * OSZ;
    unsigned short* Ab    = coefb + (size_t)OSZ * KDIM;

    prep<<<NB_CONV + NB_JAC, 256, 0, stream>>>(coef, coefb, x, Ab);

    // 16 x 2 x 8 = 256 blocks of 512 threads, exactly 1/CU; flattened with
    // XCD-bijective swizzle decoded in-kernel.
    gemm_8p<<<256, 512, 0, stream>>>(Ab, coefb, part, BATCH, OSZ, KDIM);

    int n8r = (BATCH * OSZ) / 8;                 // 262,144
    reduce_k<<<(n8r + 255) / 256, 256, 0, stream>>>(part, out, n8r);
}

// Round 5
// 104.463 us; speedup vs baseline: 1.0398x; 1.0398x over previous
//
#include <hip/hip_runtime.h>
#include <stdint.h>

// Problem constants (from reference setup_inputs)
#define BATCH 4096
#define ISZ   512
#define OSZ   512
#define KDIM  4096           // contraction dim: k = i*8 + d

// GEMM tiling (R10: 256x128 tile, BK=64, ring-3 LDS, phase-pipelined)
#define BM 256
#define BN 128
#define BK 64
#define SPLITK 4
#define KPER (KDIM / SPLITK)     // 1024
#define NT   (KPER / BK)         // 16 K-tiles per block

typedef __bf16 bf16x8 __attribute__((ext_vector_type(8)));
typedef float  f32x4  __attribute__((ext_vector_type(4)));

__device__ __forceinline__ unsigned short f2bf(float f) {
    uint32_t u = __float_as_uint(f);
    u = (u + 0x7FFFu + ((u >> 16) & 1u)) >> 16;
    return (unsigned short)u;
}

// prep: blocks [0,2048) coef fp32 [O][I][D] -> bf16 [O][K] (k-contiguous);
// blocks [2048,4096): jacobi8(tanh(x)) -> A bf16 [BATCH][KDIM], 4 x/thread.
// Jacobi computed ONCE (R7 win: in-gemm recompute was the bottleneck).
#define NB_CONV 2048         // (OSZ*KDIM/4) / 256
#define NB_JAC  2048         // (BATCH*ISZ/4) / 256
__global__ __launch_bounds__(256) void prep(
    const float* __restrict__ coef, unsigned short* __restrict__ coefb,
    const float* __restrict__ X,    unsigned short* __restrict__ Ab)
{
    const int b = blockIdx.x;
    if (b < NB_CONV) {
        int idx = b * 256 + threadIdx.x;
        float4 v = reinterpret_cast<const float4*>(coef)[idx];
        uint2 o;
        o.x = (uint32_t)f2bf(v.x) | ((uint32_t)f2bf(v.y) << 16);
        o.y = (uint32_t)f2bf(v.z) | ((uint32_t)f2bf(v.w) << 16);
        reinterpret_cast<uint2*>(coefb)[idx] = o;
    } else {
        int idx = (b - NB_CONV) * 256 + threadIdx.x;   // over [BATCH*ISZ/4]
        float4 xv = reinterpret_cast<const float4*>(X)[idx];
        const float xs[4] = {xv.x, xv.y, xv.z, xv.w};
        #pragma unroll
        for (int j = 0; j < 4; ++j) {
            // tanh(x) = 1 - 2/(exp(2x)+1); err ~1e-6 << bf16 ulp
            float e  = __expf(2.0f * xs[j]);
            float t  = 1.0f - 2.0f * __builtin_amdgcn_rcpf(e + 1.0f);
            float p0 = 1.0f;
            float p1 = 2.0f * t;
            float p2 = (1.875f     * t) * p1 - 0.75f       * p0;
            float p3 = (1.8666667f * t) * p2 - 0.8f        * p1;
            float p4 = (1.875f     * t) * p3 - 0.83333333f * p2;
            float p5 = (1.8857143f * t) * p4 - 0.85714287f * p3;
            float p6 = (1.8958333f * t) * p5 - 0.875f      * p4;
            float p7 = (1.9047619f * t) * p6 - 0.88888889f * p5;
            uint4 o;
            o.x = (uint32_t)f2bf(p0) | ((uint32_t)f2bf(p1) << 16);
            o.y = (uint32_t)f2bf(p2) | ((uint32_t)f2bf(p3) << 16);
            o.z = (uint32_t)f2bf(p4) | ((uint32_t)f2bf(p5) << 16);
            o.w = (uint32_t)f2bf(p6) | ((uint32_t)f2bf(p7) << 16);
            reinterpret_cast<uint4*>(Ab)[idx * 4 + j] = o;
        }
    }
}

#define SB  __builtin_amdgcn_sched_barrier(0)
#define BAR __builtin_amdgcn_s_barrier()
#define VM6 asm volatile("s_waitcnt vmcnt(6)" ::: "memory")
#define VM0 asm volatile("s_waitcnt vmcnt(0)" ::: "memory")

// R10 gemm: R9's phase-pipelined schedule with the WAR hazard FIXED.
// R9 bug (absmax 54.6): bq frags consumed by BOTH phase-0 and phase-1 MFMA
// of tile t, but phase 1 overwrote them with tile t+1's B before the
// phase-1 cluster -> acc[2..3] used wrong B. Fix: bq register ping-pong
// (bqP/bqQ), 2-tile-unrolled loop, static indexing (rule #20); even tiles
// consume P / prefetch Q, odd tiles the reverse. a01/a23 need no dbuf
// (fully consumed before their next write).
// Schedule (per tile, 2 phases x 16 MFMA): phase 0 = stage L(t+2) (6
// global_load_lds) + rdA23(t); BAR; MFMA acc[0..1]+=a01xbqC; edge wait
// vmcnt(6) (drains exactly L(t+1), leaves L(t+2) flying -> never vmcnt(0)
// until tail); BAR. Phase 1 = rdA01/rdB(t+1 -> bqN); BAR; MFMA
// acc[2..3]+=a23xbqC; BAR. Induction: prologue stages L0,L1 (12 loads),
// VM6 drains L0; at tile-t edge outstanding = L(t+1)+L(t+2)=12, VM6 drains
// L(t+1); t=14 edge VM0 drains L(15) (issued 2 tiles prior, cheap).
// WAR on LDS ring slot: stage(t+2) targets slot (t-1)%3, whose last
// ds_reads completed before tile t-1's phase-1 MFMA (lgkmcnt) + barriers.
// LDS XOR swizzle slot = row*8 + (c ^ (row&7)) (zero conflicts R2-R7);
// inverse on per-lane gload_lds SOURCE, LDS dest linear (rule #21).
// XCD-chunked bijective decode: per-XCD A working set 4MB ~ its L2.
__global__ __launch_bounds__(512, 2) void gemm_p(
    const unsigned short* __restrict__ Am,  // [BATCH][KDIM] bf16 bits
    const unsigned short* __restrict__ Bm,  // [OSZ][KDIM] bf16 bits
    unsigned short* __restrict__ Cp,        // [SPLITK][M][N] bf16 partials
    int M, int N, int K)
{
    __shared__ __align__(16) unsigned short As[3][BM * BK];   // 3 x 32 KB
    __shared__ __align__(16) unsigned short Bs[3][BN * BK];   // 3 x 16 KB

    const int tid  = threadIdx.x;
    const int wave = tid >> 6;
    const int lane = tid & 63;
    const int wm   = (wave >> 1) * 64;      // 4 M-groups
    const int wn   = (wave & 1) * 64;       // 2 N-groups
    const int mrow = lane & 15;
    const int kc   = lane >> 4;             // 16B chunk col (0..3) within k32

    const int wg = blockIdx.x;
    const int gx = (wg & 7) * 32 + (wg >> 3);   // XCD-chunked, bijective
    const int by = gx & 3;
    const int bx = (gx >> 2) & 15;
    const int z  = gx >> 6;

    const size_t baseA = (size_t)bx * BM * K;
    const size_t baseB = (size_t)by * BN * K;
    const int kbeg = z * KPER;

    f32x4 acc[4][4] = {};
    bf16x8 a01[2][2], a23[2][2];            // [frag][kk]
    bf16x8 bqP[4][2], bqQ[4][2];            // B frag ping-pong (R10 fix)

    // Frag LDS offsets (ushort units), loop-invariant
    int aoff[4][2], boff[4][2];
    #pragma unroll
    for (int mi = 0; mi < 4; ++mi)
        #pragma unroll
        for (int kk = 0; kk < 2; ++kk) {
            int r = wm + mi * 16 + mrow;
            aoff[mi][kk] = (r * 8 + ((kk * 4 + kc) ^ (r & 7))) * 8;
        }
    #pragma unroll
    for (int ni = 0; ni < 4; ++ni)
        #pragma unroll
        for (int kk = 0; kk < 2; ++kk) {
            int r = wn + ni * 16 + mrow;
            boff[ni][kk] = (r * 8 + ((kk * 4 + kc) ^ (r & 7))) * 8;
        }
    // Staging source offsets (inverse swizzle), loop-invariant
    int sOffA[4], sOffB[2];
    #pragma unroll
    for (int it = 0; it < 4; ++it) {
        int s = it * 512 + tid, row = s >> 3, c = (s & 7) ^ (row & 7);
        sOffA[it] = row * K + c * 8;
    }
    #pragma unroll
    for (int it = 0; it < 2; ++it) {
        int s = it * 512 + tid, row = s >> 3, c = (s & 7) ^ (row & 7);
        sOffB[it] = row * K + c * 8;
    }

    auto stageT = [&](int t, int slot) {   // 6 global_load_lds for tile t
        const unsigned short* sa = Am + baseA + kbeg + t * BK;
        unsigned short* da = &As[slot][0];
        #pragma unroll
        for (int it = 0; it < 4; ++it)
            __builtin_amdgcn_global_load_lds(
                (const __attribute__((address_space(1))) uint32_t*)(sa + sOffA[it]),
                (__attribute__((address_space(3))) uint32_t*)
                    (da + (size_t)(it * 512 + wave * 64) * 8), 16, 0, 0);
        const unsigned short* sb = Bm + baseB + kbeg + t * BK;
        unsigned short* db = &Bs[slot][0];
        #pragma unroll
        for (int it = 0; it < 2; ++it)
            __builtin_amdgcn_global_load_lds(
                (const __attribute__((address_space(1))) uint32_t*)(sb + sOffB[it]),
                (__attribute__((address_space(3))) uint32_t*)
                    (db + (size_t)(it * 512 + wave * 64) * 8), 16, 0, 0);
    };
    auto rdA01 = [&](const unsigned short* Ap) {
        #pragma unroll
        for (int m2 = 0; m2 < 2; ++m2)
            #pragma unroll
            for (int kk = 0; kk < 2; ++kk)
                a01[m2][kk] = *reinterpret_cast<const bf16x8*>(Ap + aoff[m2][kk]);
    };
    auto rdA23 = [&](const unsigned short* Ap) {
        #pragma unroll
        for (int m2 = 0; m2 < 2; ++m2)
            #pragma unroll
            for (int kk = 0; kk < 2; ++kk)
                a23[m2][kk] = *reinterpret_cast<const bf16x8*>(Ap + aoff[2 + m2][kk]);
    };
    auto rdB = [&](bf16x8 (&dst)[4][2], const unsigned short* Bp) {
        #pragma unroll
        for (int ni = 0; ni < 4; ++ni)
            #pragma unroll
            for (int kk = 0; kk < 2; ++kk)
                dst[ni][kk] = *reinterpret_cast<const bf16x8*>(Bp + boff[ni][kk]);
    };

    // One K-tile, phases 0+1. BQC = this tile's B frags; BQN = next tile's
    // (written in phase 1, consumed next tile -> no WAR).
    auto tileBody = [&](int t, bf16x8 (&BQC)[4][2], bf16x8 (&BQN)[4][2],
                        const unsigned short* Ap, const unsigned short* Apn,
                        const unsigned short* Bpn, int stageSlot) {
        // ---- PHASE 0
        if (t < NT - 2) stageT(t + 2, stageSlot);
        rdA23(Ap);
        SB; BAR; SB;
        __builtin_amdgcn_s_setprio(1);
        #pragma unroll
        for (int m2 = 0; m2 < 2; ++m2)
            #pragma unroll
            for (int ni = 0; ni < 4; ++ni)
                #pragma unroll
                for (int kk = 0; kk < 2; ++kk)
                    acc[m2][ni] = __builtin_amdgcn_mfma_f32_16x16x32_bf16(
                        a01[m2][kk], BQC[ni][kk], acc[m2][ni], 0, 0, 0);
        __builtin_amdgcn_s_setprio(0);
        SB;
        if (t < NT - 2) { VM6; } else if (t == NT - 2) { VM0; }
        BAR; SB;
        // ---- PHASE 1
        if (t < NT - 1) { rdA01(Apn); rdB(BQN, Bpn); }
        SB; BAR; SB;
        __builtin_amdgcn_s_setprio(1);
        #pragma unroll
        for (int m2 = 0; m2 < 2; ++m2)
            #pragma unroll
            for (int ni = 0; ni < 4; ++ni)
                #pragma unroll
                for (int kk = 0; kk < 2; ++kk)
                    acc[2 + m2][ni] = __builtin_amdgcn_mfma_f32_16x16x32_bf16(
                        a23[m2][kk], BQC[ni][kk], acc[2 + m2][ni], 0, 0, 0);
        __builtin_amdgcn_s_setprio(0);
        SB; BAR;
    };

    // Prologue: stage L0,L1 (12 loads); vmcnt(6) -> L0 resident, barrier;
    // read tile-0 phase-0 frags into a01/bqP.
    stageT(0, 0);
    stageT(1, 1);
    VM6;
    BAR;
    rdA01(&As[0][0]);
    rdB(bqP, &Bs[0][0]);

    // 2-tile unroll: even tile consumes bqP / prefetches bqQ; odd reverse.
    // Slots (s0,s1,s2) = LDS ring slots of tiles (t, t+1, t+2).
    int s0 = 0, s1 = 1, s2 = 2;
    for (int t = 0; t < NT; t += 2) {
        tileBody(t,     bqP, bqQ, &As[s0][0], &As[s1][0], &Bs[s1][0], s2);
        tileBody(t + 1, bqQ, bqP, &As[s1][0], &As[s2][0], &Bs[s2][0], s0);
        int tmp = s0; s0 = s2; s2 = s1; s1 = tmp;   // advance ring by 2
    }

    // bf16 partials, plain stores. C/D layout (m89-verified):
    // col = lane&15, row = (lane>>4)*4 + r
    unsigned short* Cz = Cp + (size_t)z * M * N;
    const int orow = bx * BM + wm + (lane >> 4) * 4;
    const int ocol = by * BN + wn + (lane & 15);
    #pragma unroll
    for (int mi = 0; mi < 4; ++mi)
        #pragma unroll
        for (int ni = 0; ni < 4; ++ni)
            #pragma unroll
            for (int r = 0; r < 4; ++r)
                Cz[(size_t)(orow + mi * 16 + r) * N + ocol + ni * 16] =
                    f2bf(acc[mi][ni][r]);
}

// out = sum over SPLITK bf16 partials (fp32 accumulate), 8 outputs/thread
__global__ __launch_bounds__(256) void reduce_k(
    const unsigned short* __restrict__ part, float* __restrict__ out, int n8)
{
    int idx = blockIdx.x * 256 + threadIdx.x;
    if (idx >= n8) return;
    const uint4* p = reinterpret_cast<const uint4*>(part);   // 8 bf16 / uint4
    float s[8] = {};
    #pragma unroll
    for (int z = 0; z < SPLITK; ++z) {
        uint4 v = p[(size_t)z * n8 + idx];
        s[0] += __uint_as_float((v.x & 0xFFFFu) << 16);
        s[1] += __uint_as_float(v.x & 0xFFFF0000u);
        s[2] += __uint_as_float((v.y & 0xFFFFu) << 16);
        s[3] += __uint_as_float(v.y & 0xFFFF0000u);
        s[4] += __uint_as_float((v.z & 0xFFFFu) << 16);
        s[5] += __uint_as_float(v.z & 0xFFFF0000u);
        s[6] += __uint_as_float((v.w & 0xFFFFu) << 16);
        s[7] += __uint_as_float(v.w & 0xFFFF0000u);
    }
    float4 o0 = {s[0], s[1], s[2], s[3]};
    float4 o1 = {s[4], s[5], s[6], s[7]};
    reinterpret_cast<float4*>(out)[2 * idx]     = o0;
    reinterpret_cast<float4*>(out)[2 * idx + 1] = o1;
}

extern "C" void kernel_launch(void* const* d_in, const int* in_sizes, int n_in,
                              void* d_out, int out_size, void* d_ws, size_t ws_size,
                              hipStream_t stream)
{
    const float* x    = (const float*)d_in[0];   // [4096][512]
    const float* coef = (const float*)d_in[1];   // [512][512][8]
    float* out = (float*)d_out;                  // [4096][512]

    // workspace: bf16 partials [SPLITK][4096][512] (16.8 MB)
    //          + coef bf16 [512][4096]             (4.2 MB)
    //          + A bf16 [4096][4096]               (33.5 MB)
    unsigned short* part  = (unsigned short*)d_ws;
    unsigned short* coefb = part  + (size_t)SPLITK * BATCH * OSZ;
    unsigned short* Ab    = coefb + (size_t)OSZ * KDIM;

    prep<<<NB_CONV + NB_JAC, 256, 0, stream>>>(coef, coefb, x, Ab);

    // 16(bx) x 4(by) x 4(z) = 256 blocks of 512 threads, 1/CU; flattened
    // with XCD-chunked bijective swizzle decoded in-kernel.
    gemm_p<<<256, 512, 0, stream>>>(Ab, coefb, part, BATCH, OSZ, KDIM);

    int n8r = (BATCH * OSZ) / 8;                 // 262,144
    reduce_k<<<(n8r + 255) / 256, 256, 0, stream>>>(part, out, n8r);
}

// Round 7
// 103.224 us; speedup vs baseline: 1.0522x; 1.0120x over previous
//
#include <hip/hip_runtime.h>
#include <stdint.h>

// Problem constants (from reference setup_inputs)
#define BATCH 4096
#define ISZ   512
#define OSZ   512
#define KDIM  4096           // contraction dim: k = i*8 + d

// GEMM tiling (R11 = R7 structure: 128x128 tile, BK=64, 256 thr, 2 blk/CU;
// + A ring-3 / B dbuf with counted vmcnt(4) edges instead of __syncthreads)
#define TM 128
#define TN 128
#define BK 64
#define SPLITK 4

typedef __bf16 bf16x8 __attribute__((ext_vector_type(8)));
typedef float  f32x4  __attribute__((ext_vector_type(4)));

__device__ __forceinline__ unsigned short f2bf(float f) {
    uint32_t u = __float_as_uint(f);
    u = (u + 0x7FFFu + ((u >> 16) & 1u)) >> 16;
    return (unsigned short)u;
}

// prep: blocks [0,2048) coef fp32 [O][I][D] -> bf16 [O][K] (k-contiguous);
// blocks [2048,4096): jacobi8(tanh(x)) -> A bf16 [BATCH][KDIM], 4 x/thread.
// Jacobi computed ONCE (R7 win: in-gemm recompute was the bottleneck).
#define NB_CONV 2048         // (OSZ*KDIM/4) / 256
#define NB_JAC  2048         // (BATCH*ISZ/4) / 256
__global__ __launch_bounds__(256) void prep(
    const float* __restrict__ coef, unsigned short* __restrict__ coefb,
    const float* __restrict__ X,    unsigned short* __restrict__ Ab)
{
    const int b = blockIdx.x;
    if (b < NB_CONV) {
        int idx = b * 256 + threadIdx.x;
        float4 v = reinterpret_cast<const float4*>(coef)[idx];
        uint2 o;
        o.x = (uint32_t)f2bf(v.x) | ((uint32_t)f2bf(v.y) << 16);
        o.y = (uint32_t)f2bf(v.z) | ((uint32_t)f2bf(v.w) << 16);
        reinterpret_cast<uint2*>(coefb)[idx] = o;
    } else {
        int idx = (b - NB_CONV) * 256 + threadIdx.x;   // over [BATCH*ISZ/4]
        float4 xv = reinterpret_cast<const float4*>(X)[idx];
        const float xs[4] = {xv.x, xv.y, xv.z, xv.w};
        #pragma unroll
        for (int j = 0; j < 4; ++j) {
            // tanh(x) = 1 - 2/(exp(2x)+1); err ~1e-6 << bf16 ulp
            float e  = __expf(2.0f * xs[j]);
            float t  = 1.0f - 2.0f * __builtin_amdgcn_rcpf(e + 1.0f);
            float p0 = 1.0f;
            float p1 = 2.0f * t;
            float p2 = (1.875f     * t) * p1 - 0.75f       * p0;
            float p3 = (1.8666667f * t) * p2 - 0.8f        * p1;
            float p4 = (1.875f     * t) * p3 - 0.83333333f * p2;
            float p5 = (1.8857143f * t) * p4 - 0.85714287f * p3;
            float p6 = (1.8958333f * t) * p5 - 0.875f      * p4;
            float p7 = (1.9047619f * t) * p6 - 0.88888889f * p5;
            uint4 o;
            o.x = (uint32_t)f2bf(p0) | ((uint32_t)f2bf(p1) << 16);
            o.y = (uint32_t)f2bf(p2) | ((uint32_t)f2bf(p3) << 16);
            o.z = (uint32_t)f2bf(p4) | ((uint32_t)f2bf(p5) << 16);
            o.w = (uint32_t)f2bf(p6) | ((uint32_t)f2bf(p7) << 16);
            reinterpret_cast<uint4*>(Ab)[idx * 4 + j] = o;
        }
    }
}

#define SB  __builtin_amdgcn_sched_barrier(0)
#define VM4 asm volatile("s_waitcnt vmcnt(4)" ::: "memory")
#define VM0 asm volatile("s_waitcnt vmcnt(0)" ::: "memory")

// R11 gemm. History: R7 (96.0us total) = this structure with __syncthreads
// edges (vmcnt(0) every tile). R8 (8-phase 256^2, 1 blk/CU) = 108.6; R10
// (pipelined 256x128, 1 blk/CU) = 104.5 -> deep pipelines LOSE the 2nd
// co-resident block whose implicit overlap (m114) out-performs them.
// R11 keeps R7's 2 blk/CU and relaxes only the edge wait:
//   A ring-3 (prefetch dist 2, 48KB) + B dbuf (dist 1, 32KB) = 80KB LDS
//   -> still exactly 2 blocks/CU (160KB).
// Per tile t: issue stageB(t+1) THEN stageA(t+2) (FIFO order matters);
// compute; edge = vmcnt(4) + raw s_barrier. Induction (4 loads per stage
// per wave): outstanding at edge = A(t+1)[4, issued t-1] + B(t+1)[4] +
// A(t+2)[4] = 12; vmcnt(4) drains A(t+1),B(t+1) exactly, leaves A(t+2)
// flying across the barrier (T4 counted-wait; never vmcnt(0) until tail).
// A(t+1) got a full extra tile of latency cover -> only B's same-tile
// loads remain exposed at the edge (~half of R7's drain).
// Prologue: A(0),B(0),A(1); vmcnt(4) leaves A(1). Tail: t=niter-2 has no
// A-issue -> vmcnt(0) (cheap: those loads issued >=1 tile prior); last
// tile needs no edge. WAR safety: stage targets buffers last READ in tile
// t-1, and tile t-1's frag reads are consumed by its MFMAs (lgkmcnt)
// before the t-1 edge barrier that every wave crossed before these issues.
// Raw s_barrier is pinned with sched_barrier(0) (m201 pattern) so hipcc
// cannot move memory ops across it. Compute loop, LDS XOR swizzle
// (slot = row*8 + (c ^ (row&7)), zero conflicts R2-R7, inverse on the
// per-lane gload_lds SOURCE, linear dest per contract), and epilogue are
// byte-identical to R7.
__global__ __launch_bounds__(256, 2) void gemm_fused(
    const unsigned short* __restrict__ Am,  // [BATCH][KDIM] bf16 bits
    const unsigned short* __restrict__ Bm,  // [OSZ][KDIM] bf16 bits
    unsigned short* __restrict__ Cp,        // [SPLITK][M][N] bf16 partials
    int M, int N, int K)
{
    __shared__ __align__(16) unsigned short As[3][TM * BK];   // 3 x 16 KB
    __shared__ __align__(16) unsigned short Bs[2][TN * BK];   // 2 x 16 KB

    const int tid  = threadIdx.x;
    const int wave = tid >> 6;
    const int lane = tid & 63;
    const int wm   = (wave >> 1) * 64;      // wave row offset in tile
    const int wn   = (wave & 1) * 64;       // wave col offset in tile

    const size_t baseA = (size_t)blockIdx.x * TM * K;
    const size_t baseB = (size_t)blockIdx.y * TN * K;
    const int kper  = K / SPLITK;           // 1024
    const int kbeg  = blockIdx.z * kper;
    const int niter = kper / BK;            // 16

    f32x4 acc[4][4] = {};

    const int mrow = lane & 15;             // m within 16x16 tile
    const int kc   = lane >> 4;             // 16B-chunk column offset within k

    // Staging: 128x64 bf16 = 16 KB = 1024 chunks of 16B; 256 thr x 4 its.
    // Dest chunk s is linear (wave-uniform base + lane*16); source col is
    // pre-swizzled so LDS chunk (row, sc) holds global col sc ^ (row&7).
    auto stage = [&](const unsigned short* __restrict__ G, size_t gbase,
                     unsigned short* lds, int k0) {
        #pragma unroll
        for (int it = 0; it < 4; ++it) {
            int s    = it * 256 + tid;
            int row  = s >> 3;
            int csrc = (s & 7) ^ (row & 7);
            const unsigned short* g = G + gbase + (size_t)row * K + k0 + csrc * 8;
            unsigned short* l = lds + (size_t)(it * 256 + wave * 64) * 8;
            __builtin_amdgcn_global_load_lds(
                (const __attribute__((address_space(1))) uint32_t*)g,
                (__attribute__((address_space(3))) uint32_t*)l, 16, 0, 0);
        }
    };

    // Prologue: A(0), B(0), A(1) = 12 loads; vmcnt(4) drains A(0),B(0),
    // leaves A(1) in flight.
    stage(Am, baseA, &As[0][0], kbeg);
    stage(Bm, baseB, &Bs[0][0], kbeg);
    stage(Am, baseA, &As[1][0], kbeg + BK);
    SB; VM4; __builtin_amdgcn_s_barrier(); SB;

    for (int kt = 0; kt < niter; ++kt) {
        const int k0 = kbeg + kt * BK;
        const int p  = kt & 1;
        // Issue order B(t+1) then A(t+2): keeps FIFO queue
        // [A(t+1), B(t+1), A(t+2)] so vmcnt(4) splits it correctly.
        if (kt + 1 < niter) stage(Bm, baseB, &Bs[1 - p][0], k0 + BK);
        if (kt + 2 < niter) stage(Am, baseA, &As[(kt + 2) % 3][0], k0 + 2 * BK);

        const unsigned short* Ap = &As[kt % 3][0];
        const unsigned short* Bp = &Bs[p][0];
        #pragma unroll
        for (int ks = 0; ks < BK; ks += 32) {
            bf16x8 aF[4], bF[4];
            const int cbase = (ks >> 3) + kc;
            #pragma unroll
            for (int mi = 0; mi < 4; ++mi) {
                int r = wm + mi * 16 + mrow;
                int slot = r * 8 + (cbase ^ (r & 7));
                aF[mi] = *reinterpret_cast<const bf16x8*>(Ap + (size_t)slot * 8);
            }
            #pragma unroll
            for (int ni = 0; ni < 4; ++ni) {
                int r = wn + ni * 16 + mrow;
                int slot = r * 8 + (cbase ^ (r & 7));
                bF[ni] = *reinterpret_cast<const bf16x8*>(Bp + (size_t)slot * 8);
            }
            #pragma unroll
            for (int mi = 0; mi < 4; ++mi)
                #pragma unroll
                for (int ni = 0; ni < 4; ++ni)
                    acc[mi][ni] = __builtin_amdgcn_mfma_f32_16x16x32_bf16(
                        aF[mi], bF[ni], acc[mi][ni], 0, 0, 0);
        }

        // Edge: counted wait, raw barrier (NOT __syncthreads -> no vmcnt(0))
        if (kt + 2 < niter) {
            SB; VM4; __builtin_amdgcn_s_barrier(); SB;
        } else if (kt + 1 < niter) {
            SB; VM0; __builtin_amdgcn_s_barrier(); SB;
        }
        // last tile: no edge needed (epilogue reads registers only)
    }

    // bf16 partials, plain stores (no atomics).
    // C/D layout (m89-verified): col = lane&15, row = (lane>>4)*4 + r
    unsigned short* Cz = Cp + (size_t)blockIdx.z * M * N;
    const int orow = blockIdx.x * TM + wm + (lane >> 4) * 4;
    const int ocol = blockIdx.y * TN + wn + (lane & 15);
    #pragma unroll
    for (int mi = 0; mi < 4; ++mi)
        #pragma unroll
        for (int ni = 0; ni < 4; ++ni)
            #pragma unroll
            for (int r = 0; r < 4; ++r)
                Cz[(size_t)(orow + mi * 16 + r) * N + ocol + ni * 16] =
                    f2bf(acc[mi][ni][r]);
}

// out = sum over SPLITK bf16 partials (fp32 accumulate), 8 outputs/thread
__global__ __launch_bounds__(256) void reduce_k(
    const unsigned short* __restrict__ part, float* __restrict__ out, int n8)
{
    int idx = blockIdx.x * 256 + threadIdx.x;
    if (idx >= n8) return;
    const uint4* p = reinterpret_cast<const uint4*>(part);   // 8 bf16 / uint4
    float s[8] = {};
    #pragma unroll
    for (int z = 0; z < SPLITK; ++z) {
        uint4 v = p[(size_t)z * n8 + idx];
        s[0] += __uint_as_float((v.x & 0xFFFFu) << 16);
        s[1] += __uint_as_float(v.x & 0xFFFF0000u);
        s[2] += __uint_as_float((v.y & 0xFFFFu) << 16);
        s[3] += __uint_as_float(v.y & 0xFFFF0000u);
        s[4] += __uint_as_float((v.z & 0xFFFFu) << 16);
        s[5] += __uint_as_float(v.z & 0xFFFF0000u);
        s[6] += __uint_as_float((v.w & 0xFFFFu) << 16);
        s[7] += __uint_as_float(v.w & 0xFFFF0000u);
    }
    float4 o0 = {s[0], s[1], s[2], s[3]};
    float4 o1 = {s[4], s[5], s[6], s[7]};
    reinterpret_cast<float4*>(out)[2 * idx]     = o0;
    reinterpret_cast<float4*>(out)[2 * idx + 1] = o1;
}

extern "C" void kernel_launch(void* const* d_in, const int* in_sizes, int n_in,
                              void* d_out, int out_size, void* d_ws, size_t ws_size,
                              hipStream_t stream)
{
    const float* x    = (const float*)d_in[0];   // [4096][512]
    const float* coef = (const float*)d_in[1];   // [512][512][8]
    float* out = (float*)d_out;                  // [4096][512]

    // workspace: bf16 partials [SPLITK][4096][512] (16.8 MB)
    //          + coef bf16 [512][4096]             (4.2 MB)
    //          + A bf16 [4096][4096]               (33.5 MB)
    unsigned short* part  = (unsigned short*)d_ws;
    unsigned short* coefb = part  + (size_t)SPLITK * BATCH * OSZ;
    unsigned short* Ab    = coefb + (size_t)OSZ * KDIM;

    prep<<<NB_CONV + NB_JAC, 256, 0, stream>>>(coef, coefb, x, Ab);

    dim3 grid(BATCH / TM, OSZ / TN, SPLITK);     // 32 x 4 x 4 = 512 blocks
    gemm_fused<<<grid, 256, 0, stream>>>(Ab, coefb, part, BATCH, OSZ, KDIM);

    int n8r = (BATCH * OSZ) / 8;                 // 262,144
    reduce_k<<<(n8r + 255) / 256, 256, 0, stream>>>(part, out, n8r);
}

// Round 9
// 101.792 us; speedup vs baseline: 1.0670x; 1.0141x over previous
//
#include <hip/hip_runtime.h>
#include <stdint.h>

// Problem constants (from reference setup_inputs)
#define BATCH 4096
#define ISZ   512
#define OSZ   512
#define KDIM  4096           // contraction dim: k = i*8 + d

// GEMM tiling (R12 = R7 revert: 128x128 tile, BK=64, 256 thr, 2 blk/CU,
// __syncthreads edges). R8/R10/R11 schedule surgeries ALL regressed:
// R8 8-phase 256^2 (1 blk/CU) = 108.6; R10 pipelined 256x128 (1 blk/CU)
// = 104.5; R11 counted-vmcnt edges (2 blk/CU, 80KB ring) = 103.2 vs R7
// 96.0. Lesson (matches m131-m141): at 2 blocks/CU the implicit wave
// overlap already hides the barrier drain; sched_barrier pins + extra
// LDS buffers only subtract. This file is byte-identical in codegen to
// the measured 96.0us R7 artifact.
#define TM 128
#define TN 128
#define BK 64
#define SPLITK 4

typedef __bf16 bf16x8 __attribute__((ext_vector_type(8)));
typedef float  f32x4  __attribute__((ext_vector_type(4)));

__device__ __forceinline__ unsigned short f2bf(float f) {
    uint32_t u = __float_as_uint(f);
    u = (u + 0x7FFFu + ((u >> 16) & 1u)) >> 16;
    return (unsigned short)u;
}

// prep: blocks [0,2048) coef fp32 [O][I][D] -> bf16 [O][K] (k-contiguous);
// blocks [2048,4096): jacobi8(tanh(x)) -> A bf16 [BATCH][KDIM], 4 x/thread.
// Jacobi computed ONCE (R7 win: in-gemm recompute was the bottleneck).
#define NB_CONV 2048         // (OSZ*KDIM/4) / 256
#define NB_JAC  2048         // (BATCH*ISZ/4) / 256
__global__ __launch_bounds__(256) void prep(
    const float* __restrict__ coef, unsigned short* __restrict__ coefb,
    const float* __restrict__ X,    unsigned short* __restrict__ Ab)
{
    const int b = blockIdx.x;
    if (b < NB_CONV) {
        int idx = b * 256 + threadIdx.x;
        float4 v = reinterpret_cast<const float4*>(coef)[idx];
        uint2 o;
        o.x = (uint32_t)f2bf(v.x) | ((uint32_t)f2bf(v.y) << 16);
        o.y = (uint32_t)f2bf(v.z) | ((uint32_t)f2bf(v.w) << 16);
        reinterpret_cast<uint2*>(coefb)[idx] = o;
    } else {
        int idx = (b - NB_CONV) * 256 + threadIdx.x;   // over [BATCH*ISZ/4]
        float4 xv = reinterpret_cast<const float4*>(X)[idx];
        const float xs[4] = {xv.x, xv.y, xv.z, xv.w};
        #pragma unroll
        for (int j = 0; j < 4; ++j) {
            // tanh(x) = 1 - 2/(exp(2x)+1); err ~1e-6 << bf16 ulp
            float e  = __expf(2.0f * xs[j]);
            float t  = 1.0f - 2.0f * __builtin_amdgcn_rcpf(e + 1.0f);
            float p0 = 1.0f;
            float p1 = 2.0f * t;
            float p2 = (1.875f     * t) * p1 - 0.75f       * p0;
            float p3 = (1.8666667f * t) * p2 - 0.8f        * p1;
            float p4 = (1.875f     * t) * p3 - 0.83333333f * p2;
            float p5 = (1.8857143f * t) * p4 - 0.85714287f * p3;
            float p6 = (1.8958333f * t) * p5 - 0.875f      * p4;
            float p7 = (1.9047619f * t) * p6 - 0.88888889f * p5;
            uint4 o;
            o.x = (uint32_t)f2bf(p0) | ((uint32_t)f2bf(p1) << 16);
            o.y = (uint32_t)f2bf(p2) | ((uint32_t)f2bf(p3) << 16);
            o.z = (uint32_t)f2bf(p4) | ((uint32_t)f2bf(p5) << 16);
            o.w = (uint32_t)f2bf(p6) | ((uint32_t)f2bf(p7) << 16);
            reinterpret_cast<uint4*>(Ab)[idx * 4 + j] = o;
        }
    }
}

// Pure bf16 GEMM, split-K partials with plain stores.
// Structure history: R3 atomics = ~50us TCC serialization (removed);
// R5 in-register A = 2x duplicated VALU (reverted); R6 = shared-A-via-LDS
// jacobi fusion; R7 = jacobi hoisted to prep. Both A and B stage via
// global_load_lds (16B chunks), double-buffered, prefetch-distance-1:
// next tile's async loads fly through this tile's MFMA phase; the
// __syncthreads edge drains them (vmcnt(0)) — measured BEST for this
// occupancy (R8/R10/R11 counted-vmcnt variants all slower).
// 128x128 block tile, BK=64, 256 threads = 4 waves (2x2), wave tile 64x64
// via 4x4 of mfma_f32_16x16x32_bf16 (layout verified R1-R5).
// LDS XOR swizzle: slot = row*8 + (c ^ (row&7)); global_load_lds keeps
// its wave-uniform-base + lane*16 dest contract (swizzle applied on the
// per-lane SOURCE address). SQ_LDS_BANK_CONFLICT == 0 measured R2-R7.
__global__ __launch_bounds__(256, 2) void gemm_fused(
    const unsigned short* __restrict__ Am,  // [BATCH][KDIM] bf16 bits
    const unsigned short* __restrict__ Bm,  // [OSZ][KDIM] bf16 bits
    unsigned short* __restrict__ Cp,        // [SPLITK][M][N] bf16 partials
    int M, int N, int K)
{
    __shared__ __align__(16) unsigned short As[2][TM * BK];   // 2 x 16 KB
    __shared__ __align__(16) unsigned short Bs[2][TN * BK];   // 2 x 16 KB

    const int tid  = threadIdx.x;
    const int wave = tid >> 6;
    const int lane = tid & 63;
    const int wm   = (wave >> 1) * 64;      // wave row offset in tile
    const int wn   = (wave & 1) * 64;       // wave col offset in tile

    const size_t baseA = (size_t)blockIdx.x * TM * K;
    const size_t baseB = (size_t)blockIdx.y * TN * K;
    const int kper  = K / SPLITK;           // 1024
    const int kbeg  = blockIdx.z * kper;
    const int niter = kper / BK;            // 16

    f32x4 acc[4][4] = {};

    const int mrow = lane & 15;             // m within 16x16 tile
    const int kc   = lane >> 4;             // 16B-chunk column offset within k

    // Staging: 128x64 bf16 = 16 KB = 1024 chunks of 16B; 256 thr x 4 its.
    // Dest chunk s is linear (wave-uniform base + lane*16); source col is
    // pre-swizzled so LDS chunk (row, sc) holds global col sc ^ (row&7).
    auto stage = [&](const unsigned short* __restrict__ G, size_t gbase,
                     unsigned short* lds, int k0) {
        #pragma unroll
        for (int it = 0; it < 4; ++it) {
            int s    = it * 256 + tid;
            int row  = s >> 3;
            int csrc = (s & 7) ^ (row & 7);
            const unsigned short* g = G + gbase + (size_t)row * K + k0 + csrc * 8;
            unsigned short* l = lds + (size_t)(it * 256 + wave * 64) * 8;
            __builtin_amdgcn_global_load_lds(
                (const __attribute__((address_space(1))) uint32_t*)g,
                (__attribute__((address_space(3))) uint32_t*)l, 16, 0, 0);
        }
    };

    stage(Bm, baseB, &Bs[0][0], kbeg);
    stage(Am, baseA, &As[0][0], kbeg);
    __syncthreads();

    for (int kt = 0; kt < niter; ++kt) {
        const int k0 = kbeg + kt * BK;
        const int p  = kt & 1;
        if (kt + 1 < niter) {
            stage(Bm, baseB, &Bs[1 - p][0], k0 + BK);  // async, flies through
            stage(Am, baseA, &As[1 - p][0], k0 + BK);  // the MFMA phase
        }

        const unsigned short* Ap = &As[p][0];
        const unsigned short* Bp = &Bs[p][0];
        #pragma unroll
        for (int ks = 0; ks < BK; ks += 32) {
            bf16x8 aF[4], bF[4];
            const int cbase = (ks >> 3) + kc;
            #pragma unroll
            for (int mi = 0; mi < 4; ++mi) {
                int r = wm + mi * 16 + mrow;
                int slot = r * 8 + (cbase ^ (r & 7));
                aF[mi] = *reinterpret_cast<const bf16x8*>(Ap + (size_t)slot * 8);
            }
            #pragma unroll
            for (int ni = 0; ni < 4; ++ni) {
                int r = wn + ni * 16 + mrow;
                int slot = r * 8 + (cbase ^ (r & 7));
                bF[ni] = *reinterpret_cast<const bf16x8*>(Bp + (size_t)slot * 8);
            }
            #pragma unroll
            for (int mi = 0; mi < 4; ++mi)
                #pragma unroll
                for (int ni = 0; ni < 4; ++ni)
                    acc[mi][ni] = __builtin_amdgcn_mfma_f32_16x16x32_bf16(
                        aF[mi], bF[ni], acc[mi][ni], 0, 0, 0);
        }
        __syncthreads();   // completes buf[1-p] stage; fences buf[p] reuse
    }

    // bf16 partials, plain stores (no atomics).
    // C/D layout (m89-verified): col = lane&15, row = (lane>>4)*4 + r
    unsigned short* Cz = Cp + (size_t)blockIdx.z * M * N;
    const int orow = blockIdx.x * TM + wm + (lane >> 4) * 4;
    const int ocol = blockIdx.y * TN + wn + (lane & 15);
    #pragma unroll
    for (int mi = 0; mi < 4; ++mi)
        #pragma unroll
        for (int ni = 0; ni < 4; ++ni)
            #pragma unroll
            for (int r = 0; r < 4; ++r)
                Cz[(size_t)(orow + mi * 16 + r) * N + ocol + ni * 16] =
                    f2bf(acc[mi][ni][r]);
}

// out = sum over SPLITK bf16 partials (fp32 accumulate), 8 outputs/thread
__global__ __launch_bounds__(256) void reduce_k(
    const unsigned short* __restrict__ part, float* __restrict__ out, int n8)
{
    int idx = blockIdx.x * 256 + threadIdx.x;
    if (idx >= n8) return;
    const uint4* p = reinterpret_cast<const uint4*>(part);   // 8 bf16 / uint4
    float s[8] = {};
    #pragma unroll
    for (int z = 0; z < SPLITK; ++z) {
        uint4 v = p[(size_t)z * n8 + idx];
        s[0] += __uint_as_float((v.x & 0xFFFFu) << 16);
        s[1] += __uint_as_float(v.x & 0xFFFF0000u);
        s[2] += __uint_as_float((v.y & 0xFFFFu) << 16);
        s[3] += __uint_as_float(v.y & 0xFFFF0000u);
        s[4] += __uint_as_float((v.z & 0xFFFFu) << 16);
        s[5] += __uint_as_float(v.z & 0xFFFF0000u);
        s[6] += __uint_as_float((v.w & 0xFFFFu) << 16);
        s[7] += __uint_as_float(v.w & 0xFFFF0000u);
    }
    float4 o0 = {s[0], s[1], s[2], s[3]};
    float4 o1 = {s[4], s[5], s[6], s[7]};
    reinterpret_cast<float4*>(out)[2 * idx]     = o0;
    reinterpret_cast<float4*>(out)[2 * idx + 1] = o1;
}

extern "C" void kernel_launch(void* const* d_in, const int* in_sizes, int n_in,
                              void* d_out, int out_size, void* d_ws, size_t ws_size,
                              hipStream_t stream)
{
    const float* x    = (const float*)d_in[0];   // [4096][512]
    const float* coef = (const float*)d_in[1];   // [512][512][8]
    float* out = (float*)d_out;                  // [4096][512]

    // workspace: bf16 partials [SPLITK][4096][512] (16.8 MB)
    //          + coef bf16 [512][4096]             (4.2 MB)
    //          + A bf16 [4096][4096]               (33.5 MB)
    unsigned short* part  = (unsigned short*)d_ws;
    unsigned short* coefb = part  + (size_t)SPLITK * BATCH * OSZ;
    unsigned short* Ab    = coefb + (size_t)OSZ * KDIM;

    prep<<<NB_CONV + NB_JAC, 256, 0, stream>>>(coef, coefb, x, Ab);

    dim3 grid(BATCH / TM, OSZ / TN, SPLITK);     // 32 x 4 x 4 = 512 blocks
    gemm_fused<<<grid, 256, 0, stream>>>(Ab, coefb, part, BATCH, OSZ, KDIM);

    int n8r = (BATCH * OSZ) / 8;                 // 262,144
    reduce_k<<<(n8r + 255) / 256, 256, 0, stream>>>(part, out, n8r);
}